// Round 2
// baseline (684.928 us; speedup 1.0000x reference)
//
#include <hip/hip_runtime.h>

// B=1, H=32, N=T=2048, D=128, R=64
// out[h,n,t] = sum_d q[h,n,d]*kq[h,t,d] + (1/64)*sum_r (q@G)[h,n,r]*sign((ko-kq)@G)[h,t,r]
// Augmented-K GEMM: Qb[h][n][0:128]=bf16(q), Qb[..][128:192]=bf16(q@G)
//                   Kb[h][t][0:128]=bf16(kq), Kb[..][128:192]=sign*(1/64)
// v3: GEMM -> barrier-free strip kernel. A (128x192) lives in registers per wave,
//     B streamed from global (L2) with half-K prefetch, C stored nontemporal.
//     Head->XCD pinning keeps each head's Kb resident in one XCD's L2.

#define H 32
#define NQ 2048
#define NT 2048
#define D 128
#define R 64
#define KDIM 192

typedef __attribute__((ext_vector_type(4))) float f32x4;
typedef __attribute__((ext_vector_type(8))) short bf16x8;

__device__ __forceinline__ short f2bf(float x) {  // RNE f32->bf16
  union { float f; unsigned u; } v; v.f = x;
  unsigned r = v.u + 0x7fff + ((v.u >> 16) & 1);
  return (short)(r >> 16);
}
__device__ __forceinline__ float bf2f(short h) {
  union { unsigned u; float f; } v; v.u = ((unsigned)(unsigned short)h) << 16;
  return v.f;
}

// ---- prep: blocks [0,512) build Kb (sign path, hi/lo split MFMA);
//            blocks [512,1024) build Qb (q@G single-MFMA). 128 rows/block.
__global__ __launch_bounds__(256, 2) void prep(
    const float* __restrict__ q, const float* __restrict__ ko,
    const float* __restrict__ kq, const float* __restrict__ G,
    short* __restrict__ Qb, short* __restrict__ Kb) {
  const int tid = threadIdx.x, lane = tid & 63, wave = tid >> 6;
  const int quad = lane >> 4, mrow = lane & 15;
  const bool kmode = blockIdx.x < (H * NT / 128);
  const long blk = kmode ? blockIdx.x : (blockIdx.x - H * NT / 128);
  const long rbase = blk * 128 + wave * 32;  // wave owns 32 rows
  short* outb = kmode ? Kb : Qb;

  f32x4 acc[2][4] = {};

  for (int ks = 0; ks < 4; ++ks) {
    const int d0 = ks * 32 + quad * 8;
    // B-operand: columns of G. lane layout: n=j*16+mrow, k=quad*8+e.
    bf16x8 gh[4], gl[4];
#pragma unroll
    for (int j = 0; j < 4; ++j) {
      const float* gp = G + (size_t)d0 * R + j * 16 + mrow;
#pragma unroll
      for (int e = 0; e < 8; ++e) {
        float g = gp[(size_t)e * R];       // 4B gather, 64B-coalesced per quad, L1/L2-hot
        short hb = f2bf(g);
        gh[j][e] = hb;
        gl[j][e] = f2bf(g - bf2f(hb));
      }
    }
    // A-operand: rows of E=ko-kq (kmode) or q. Lane layout: m=mrow, k=quad*8+e.
    bf16x8 ah[2], al[2];
#pragma unroll
    for (int i = 0; i < 2; ++i) {
      const long row = rbase + i * 16 + mrow;
      if (kmode) {
        const f32x4 a0 = *(const f32x4*)(ko + row * D + d0);
        const f32x4 a1 = *(const f32x4*)(ko + row * D + d0 + 4);
        const f32x4 b0 = *(const f32x4*)(kq + row * D + d0);
        const f32x4 b1 = *(const f32x4*)(kq + row * D + d0 + 4);
        bf16x8 kqb;
#pragma unroll
        for (int t = 0; t < 4; ++t) {
          kqb[t] = f2bf(b0[t]); kqb[t + 4] = f2bf(b1[t]);
          float e0 = a0[t] - b0[t];
          short h0 = f2bf(e0); ah[i][t] = h0; al[i][t] = f2bf(e0 - bf2f(h0));
          float e1 = a1[t] - b1[t];
          short h1 = f2bf(e1); ah[i][t + 4] = h1; al[i][t + 4] = f2bf(e1 - bf2f(h1));
        }
        *(bf16x8*)(Kb + row * KDIM + d0) = kqb;  // bf16(kq) copy, 16B store
      } else {
        const f32x4 a0 = *(const f32x4*)(q + row * D + d0);
        const f32x4 a1 = *(const f32x4*)(q + row * D + d0 + 4);
        bf16x8 qb;
#pragma unroll
        for (int t = 0; t < 4; ++t) {
          short h0 = f2bf(a0[t]); qb[t] = h0; ah[i][t] = h0; al[i][t] = 0;
          short h1 = f2bf(a1[t]); qb[t + 4] = h1; ah[i][t + 4] = h1; al[i][t + 4] = 0;
        }
        *(bf16x8*)(Qb + row * KDIM + d0) = qb;   // bf16(q) copy, 16B store
      }
    }
#pragma unroll
    for (int i = 0; i < 2; ++i)
#pragma unroll
      for (int j = 0; j < 4; ++j) {
        acc[i][j] = __builtin_amdgcn_mfma_f32_16x16x32_bf16(ah[i], gh[j], acc[i][j], 0, 0, 0);
        if (kmode) {  // hi/lo split: ~f32-accurate projection so signs don't flip
          acc[i][j] = __builtin_amdgcn_mfma_f32_16x16x32_bf16(al[i], gh[j], acc[i][j], 0, 0, 0);
          acc[i][j] = __builtin_amdgcn_mfma_f32_16x16x32_bf16(ah[i], gl[j], acc[i][j], 0, 0, 0);
        }
      }
  }
  // C/D layout: col = mrow, row = quad*4 + r within each 16x16 tile.
#pragma unroll
  for (int i = 0; i < 2; ++i)
#pragma unroll
    for (int j = 0; j < 4; ++j)
#pragma unroll
      for (int r = 0; r < 4; ++r) {
        const long row = rbase + i * 16 + quad * 4 + r;
        const int col = j * 16 + mrow;
        float v = acc[i][j][r];
        short s;
        if (kmode)  // +-1/64 exact in bf16: 0x3C80 / 0xBC80
          s = v > 0.f ? (short)0x3C80 : (v < 0.f ? (short)0xBC80 : (short)0);
        else
          s = f2bf(v);
        outb[row * KDIM + 128 + col] = s;
      }
}

// ---- main GEMM: strip kernel. Block = 128 m-rows x 2048 n-cols of one head.
// 8 waves (512 thr): wave grid 2m x 4n, wave tile 64m x 32n per 128-n-tile.
// A-slice (64 rows x K=192) register-resident per wave. No LDS, no barriers.
__global__ __launch_bounds__(512, 2) void gemm_strip(const short* __restrict__ Qb,
                                                     const short* __restrict__ Kb,
                                                     float* __restrict__ out) {
  // head->XCD pinning: default dispatch gives XCD = blockIdx % 8 (round-robin).
  // heads on XCD x: {x, x+8, x+16, x+24}; Kb working set 4*786KB fits 4MB L2.
  const int bid = blockIdx.x;            // 0..511
  const int h = (bid & 7) + ((bid >> 3) & 3) * 8;
  const int m0 = (bid >> 5) * 128;       // 16 m-tiles

  const int tid = threadIdx.x, lane = tid & 63, wave = tid >> 6;
  const int quad = lane >> 4, mrow = lane & 15;
  const int wm = (wave >> 2) * 64;       // 0 or 64
  const int wn = (wave & 3) * 32;        // 0,32,64,96

  const short* A = Qb + (size_t)h * NQ * KDIM;
  const short* B = Kb + (size_t)h * NT * KDIM;

  // A-frags resident: af[i][kc], lane holds A[m = mrow][k = quad*8 + e]
  bf16x8 af[4][6];
#pragma unroll
  for (int i = 0; i < 4; ++i) {
    const short* ap = A + (size_t)(m0 + wm + i * 16 + mrow) * KDIM + quad * 8;
#pragma unroll
    for (int kc = 0; kc < 6; ++kc) af[i][kc] = *(const bf16x8*)(ap + kc * 32);
  }

  // B base for this wave's n-columns: nrow(t, j) = t*128 + wn + j*16 + mrow
  const short* bbase = B + (size_t)(wn + mrow) * KDIM + quad * 8;

  f32x4 acc[4][2] = {};
  bf16x8 b0[2][3], b1[2][3];

  // prologue: half0 of tile 0
#pragma unroll
  for (int j = 0; j < 2; ++j)
#pragma unroll
    for (int kc = 0; kc < 3; ++kc)
      b0[j][kc] = *(const bf16x8*)(bbase + (size_t)j * 16 * KDIM + kc * 32);

  float* obase = out + ((size_t)h * NQ + m0 + wm + quad * 4) * NT + wn + mrow;

#pragma unroll 1
  for (int t = 0; t < NT / 128; ++t) {
    const short* bt = bbase + (size_t)t * 128 * KDIM;
    // issue half1 loads for tile t
#pragma unroll
    for (int j = 0; j < 2; ++j)
#pragma unroll
      for (int kc = 0; kc < 3; ++kc)
        b1[j][kc] = *(const bf16x8*)(bt + (size_t)j * 16 * KDIM + (kc + 3) * 32);
    // MFMA half0 (k = 0..95)
#pragma unroll
    for (int kc = 0; kc < 3; ++kc)
#pragma unroll
      for (int i = 0; i < 4; ++i)
#pragma unroll
        for (int j = 0; j < 2; ++j)
          acc[i][j] = __builtin_amdgcn_mfma_f32_16x16x32_bf16(af[i][kc], b0[j][kc], acc[i][j], 0, 0, 0);
    // prefetch half0 of tile t+1
    if (t < NT / 128 - 1) {
      const short* bn = bt + (size_t)128 * KDIM;
#pragma unroll
      for (int j = 0; j < 2; ++j)
#pragma unroll
        for (int kc = 0; kc < 3; ++kc)
          b0[j][kc] = *(const bf16x8*)(bn + (size_t)j * 16 * KDIM + kc * 32);
    }
    // MFMA half1 (k = 96..191)
#pragma unroll
    for (int kc = 0; kc < 3; ++kc)
#pragma unroll
      for (int i = 0; i < 4; ++i)
#pragma unroll
        for (int j = 0; j < 2; ++j)
          acc[i][j] = __builtin_amdgcn_mfma_f32_16x16x32_bf16(af[i][kc + 3], b1[j][kc], acc[i][j], 0, 0, 0);
    // store tile t (nontemporal: write-once stream, keep Kb in L2) + clear acc
    float* op = obase + t * 128;
#pragma unroll
    for (int i = 0; i < 4; ++i)
#pragma unroll
      for (int r = 0; r < 4; ++r) {
        float* p = op + (size_t)(i * 16 + r) * NT;
#pragma unroll
        for (int j = 0; j < 2; ++j) __builtin_nontemporal_store(acc[i][j][r], p + j * 16);
      }
#pragma unroll
    for (int i = 0; i < 4; ++i)
#pragma unroll
      for (int j = 0; j < 2; ++j) acc[i][j] = (f32x4){0.f, 0.f, 0.f, 0.f};
  }
}

extern "C" void kernel_launch(void* const* d_in, const int* in_sizes, int n_in,
                              void* d_out, int out_size, void* d_ws, size_t ws_size,
                              hipStream_t stream) {
  const float* q  = (const float*)d_in[0];
  const float* ko = (const float*)d_in[1];
  const float* kq = (const float*)d_in[2];
  const float* G  = (const float*)d_in[3];
  float* out = (float*)d_out;

  short* Kb = (short*)d_ws;
  short* Qb = Kb + (size_t)H * NT * KDIM;  // total ws: 50,331,648 B

  prep<<<(H * NT + H * NQ) / 128, 256, 0, stream>>>(q, ko, kq, G, Qb, Kb);

  gemm_strip<<<512, 512, 0, stream>>>(Qb, Kb, out);
}